// Round 1
// baseline (574.023 us; speedup 1.0000x reference)
//
#include <hip/hip_runtime.h>
#include <stdint.h>

#define T_TOK 8192
#define DIM   1024
#define HID   2048
#define NE    8

#define BM 256
#define BN 256
#define BK 64

#define GB_TOK 32  // tokens per gate block

typedef float floatx4 __attribute__((ext_vector_type(4)));
typedef short shortx8 __attribute__((ext_vector_type(8)));

typedef __attribute__((address_space(3))) void       lds_void;
typedef const __attribute__((address_space(1))) void gbl_void;

__device__ __forceinline__ unsigned short f2bf(float f) {
  unsigned int u = __float_as_uint(f);
  unsigned int r = 0x7fffu + ((u >> 16) & 1u);
  return (unsigned short)((u + r) >> 16);
}

// ------------- transpose+cast: in [R][C] f32 -> out [C][R] bf16, blockIdx.z = expert -------------
__global__ __launch_bounds__(256) void transpose_cast_kernel(const float* __restrict__ in,
                                                             unsigned short* __restrict__ out,
                                                             int R, int C) {
  __shared__ float tile[32][33];
  const size_t eoff = (size_t)blockIdx.z * R * C;
  const float* ip = in + eoff;
  unsigned short* op = out + eoff;
  int c0 = blockIdx.x * 32, r0 = blockIdx.y * 32;
  int tx = threadIdx.x, ty = threadIdx.y;
#pragma unroll
  for (int i = 0; i < 4; i++)
    tile[ty + i * 8][tx] = ip[(size_t)(r0 + ty + i * 8) * C + (c0 + tx)];
  __syncthreads();
#pragma unroll
  for (int i = 0; i < 4; i++)
    op[(size_t)(c0 + ty + i * 8) * R + (r0 + tx)] = f2bf(tile[tx][ty + i * 8]);
}

// ---------------- gating: 32 tokens/block, hierarchical binning; also casts x -> bf16 ----------------
__global__ __launch_bounds__(256) void gate_kernel(const float* __restrict__ x,
                                                   const float* __restrict__ wg,
                                                   unsigned short* __restrict__ xb,
                                                   int* counts, int* top1cnt, float* ssum,
                                                   int* tok_list, float* wgt_list) {
  __shared__ int   lds_cnt[8];
  __shared__ int   lds_top1[8];
  __shared__ float lds_ssum[4][8];
  __shared__ int   tk_e[GB_TOK][2];
  __shared__ int   tk_r[GB_TOK][2];
  __shared__ float tk_w[GB_TOK][2];
  __shared__ int   base[8];

  const int tid = threadIdx.x;
  const int wave = tid >> 6;
  const int lane = tid & 63;

  if (tid < 8) { lds_cnt[tid] = 0; lds_top1[tid] = 0; }
  if (tid < 32) lds_ssum[tid >> 3][tid & 7] = 0.f;
  __syncthreads();

  float ssum_local[8];
#pragma unroll
  for (int e = 0; e < 8; e++) ssum_local[e] = 0.f;

  for (int it = 0; it < GB_TOK / 4; it++) {
    const int lt = it * 4 + wave;
    const int t = blockIdx.x * GB_TOK + lt;

    float acc[8];
#pragma unroll
    for (int e = 0; e < 8; e++) acc[e] = 0.f;
    const float* xr = x + (size_t)t * DIM;
    unsigned short* xw = xb + (size_t)t * DIM;
#pragma unroll
    for (int i = 0; i < 16; i++) {
      int d = i * 64 + lane;
      float xv = xr[d];
      xw[d] = f2bf(xv);  // fused f32->bf16 cast (replaces cast_x_kernel)
      const float4* wr = reinterpret_cast<const float4*>(wg + d * 8);
      float4 w0 = wr[0], w1 = wr[1];
      acc[0] += xv * w0.x; acc[1] += xv * w0.y; acc[2] += xv * w0.z; acc[3] += xv * w0.w;
      acc[4] += xv * w1.x; acc[5] += xv * w1.y; acc[6] += xv * w1.z; acc[7] += xv * w1.w;
    }
#pragma unroll
    for (int e = 0; e < 8; e++) {
#pragma unroll
      for (int off = 32; off > 0; off >>= 1) acc[e] += __shfl_xor(acc[e], off, 64);
    }
    if (lane == 0) {
      float mx = acc[0];
#pragma unroll
      for (int e = 1; e < 8; e++) mx = fmaxf(mx, acc[e]);
      float s[8], sum = 0.f;
#pragma unroll
      for (int e = 0; e < 8; e++) { s[e] = expf(acc[e] - mx); sum += s[e]; }
      float inv = 1.f / sum;
#pragma unroll
      for (int e = 0; e < 8; e++) { s[e] *= inv; ssum_local[e] += s[e]; }
      // top-2 (strict > : ties -> lower index, matches lax.top_k)
      int i1 = 0;
#pragma unroll
      for (int e = 1; e < 8; e++) if (s[e] > s[i1]) i1 = e;
      int i2 = (i1 == 0) ? 1 : 0;
#pragma unroll
      for (int e = 0; e < 8; e++) if (e != i1 && s[e] > s[i2]) i2 = e;
      atomicAdd(&lds_top1[i1], 1);
      int r1 = atomicAdd(&lds_cnt[i1], 1);
      int r2 = atomicAdd(&lds_cnt[i2], 1);
      tk_e[lt][0] = i1; tk_r[lt][0] = r1; tk_w[lt][0] = s[i1];
      tk_e[lt][1] = i2; tk_r[lt][1] = r2; tk_w[lt][1] = s[i2];
    }
  }
  if (lane == 0) {
#pragma unroll
    for (int e = 0; e < 8; e++) lds_ssum[wave][e] = ssum_local[e];
  }
  __syncthreads();
  if (tid < 8) {
    base[tid] = atomicAdd(&counts[tid], lds_cnt[tid]);
    atomicAdd(&top1cnt[tid], lds_top1[tid]);
    atomicAdd(&ssum[tid],
              lds_ssum[0][tid] + lds_ssum[1][tid] + lds_ssum[2][tid] + lds_ssum[3][tid]);
  }
  __syncthreads();
  if (tid < GB_TOK * 2) {
    int lt = tid >> 1, k = tid & 1;
    int e = tk_e[lt][k];
    int pos = base[e] + tk_r[lt][k];
    tok_list[e * T_TOK + pos] = blockIdx.x * GB_TOK + lt;
    wgt_list[e * T_TOK + pos] = tk_w[lt][k];
  }
}

// ---------------- scan + l_aux ----------------
__global__ void scan_kernel(const int* counts, const int* top1cnt, const float* ssum,
                            int* h_off, float* laux_out) {
  if (threadIdx.x == 0 && blockIdx.x == 0) {
    int off = 0;
    float l = 0.f;
    for (int e = 0; e < 8; e++) {
      h_off[e] = off;
      off += counts[e];
      l += (ssum[e] / (float)T_TOK) * ((float)top1cnt[e] / (float)T_TOK);
    }
    *laux_out = l * (float)NE;
  }
}

// ---------------- grouped GEMM: C = gatherA(M x K) * B^T-layout(N x K) ----------------
// 256x256 tile, BK=64, 8 waves (2M x 4N), double-buffered LDS (128 KiB), 2-phase prefetch:
//   prologue STAGE(buf0); per K-step: STAGE(buf^1, next) -> ds_read+MFMA on buf -> one barrier.
//   The compiler's vmcnt(0) drain at the barrier now lands AFTER a full MFMA phase, so the
//   prefetched loads' latency is hidden (T3 minimum-2-phase recipe).
// global_load_lds width=16 staging with XOR-swizzled chunk placement:
//   LDS row r, physical 16B-chunk c holds global chunk (c ^ (r&7))  -> 0 bank conflicts (verified).
// MODE 0: A = x_bf gathered via tok_list; epilogue relu(acc + b1) -> h_buf bf16 (stride N==HID)
// MODE 1: A = h_buf rows (h_off[e]+row);   epilogue atomicAdd(out[tok], w*(acc + b2))
template <int MODE>
__global__ __launch_bounds__(512, 2) void moe_gemm_kernel(
    const unsigned short* __restrict__ A_src, const unsigned short* __restrict__ B_src,
    const float* __restrict__ bias, const int* __restrict__ counts,
    const int* __restrict__ h_off, const int* __restrict__ tok_list,
    const float* __restrict__ wgt_list, unsigned short* __restrict__ h_out,
    float* __restrict__ out, int N, int K) {
  __shared__ unsigned short s_a[2][BM][BK];  // 64 KB
  __shared__ unsigned short s_b[2][BN][BK];  // 64 KB

  const int e = blockIdx.z;
  const int n_e = counts[e];
  const int m0 = blockIdx.y * BM;
  if (m0 >= n_e) return;
  const int n0 = blockIdx.x * BN;
  const int tid = threadIdx.x;

  const int lane = tid & 63;
  const int wv = tid >> 6;               // 0..7
  const int lrow = lane >> 3;            // 0..7  (row within 8-row DMA call)
  const int lchk = (lane & 7) ^ lrow;    // XOR-swizzled global 16B chunk index

  // per-lane global source pointers; 4 staging calls each for A and B (64 rows per call)
  const unsigned short* a_g[4];
  const unsigned short* b_g[4];
#pragma unroll
  for (int c = 0; c < 4; c++) {
    int ra = c * 64 + wv * 8 + lrow;              // tile row 0..255
    int gr = m0 + ra;
    int safe = (gr < n_e) ? gr : (n_e - 1);       // clamp: garbage only feeds discarded C rows
    const unsigned short* abase;
    if (MODE == 0) {
      int tok = tok_list[e * T_TOK + safe];
      abase = A_src + (size_t)tok * K;
    } else {
      abase = A_src + (size_t)(h_off[e] + safe) * K;
    }
    a_g[c] = abase + lchk * 8;
    b_g[c] = B_src + ((size_t)e * N + n0 + ra) * K + lchk * 8;
  }

  auto STAGE = [&](int buf, int kt) {
#pragma unroll
    for (int c = 0; c < 4; c++) {
      __builtin_amdgcn_global_load_lds((gbl_void*)(a_g[c] + kt),
                                       (lds_void*)&s_a[buf][c * 64 + wv * 8][0], 16, 0, 0);
      __builtin_amdgcn_global_load_lds((gbl_void*)(b_g[c] + kt),
                                       (lds_void*)&s_b[buf][c * 64 + wv * 8][0], 16, 0, 0);
    }
  };

  const int lm = lane & 15;
  const int quad = lane >> 4;
  const int r7 = lm & 7;                 // == row&7 for all fragment rows
  const int wm = (wv >> 2) * 128;        // wave M-offset (2 waves in M)
  const int wn = (wv & 3) * 64;          // wave N-offset (4 waves in N)

  floatx4 acc[8][4];
#pragma unroll
  for (int mi = 0; mi < 8; mi++)
#pragma unroll
    for (int ni = 0; ni < 4; ni++) acc[mi][ni] = (floatx4){0.f, 0.f, 0.f, 0.f};

  const int NT = K / BK;
  STAGE(0, 0);
  __syncthreads();

  int cur = 0;
  for (int t = 0; t < NT; ++t) {
    if (t + 1 < NT) STAGE(cur ^ 1, (t + 1) * BK);   // prefetch next K-tile into other buffer
#pragma unroll
    for (int kk = 0; kk < 2; kk++) {
      const int pc = ((kk << 2) + quad) ^ r7;       // physical chunk for this lane's fragment
      shortx8 af[8], bfr[4];
#pragma unroll
      for (int mi = 0; mi < 8; mi++)
        af[mi] = *reinterpret_cast<const shortx8*>(&s_a[cur][wm + mi * 16 + lm][pc << 3]);
#pragma unroll
      for (int ni = 0; ni < 4; ni++)
        bfr[ni] = *reinterpret_cast<const shortx8*>(&s_b[cur][wn + ni * 16 + lm][pc << 3]);
#pragma unroll
      for (int mi = 0; mi < 8; mi++)
#pragma unroll
        for (int ni = 0; ni < 4; ni++)
          acc[mi][ni] = __builtin_amdgcn_mfma_f32_16x16x32_bf16(af[mi], bfr[ni], acc[mi][ni], 0, 0, 0);
    }
    __syncthreads();  // drains prefetch vmcnt + guards buffer reuse (one barrier per K-step)
    cur ^= 1;
  }

  // epilogue: D row = quad*4 + r, col = lm (verified C/D layout)
#pragma unroll
  for (int mi = 0; mi < 8; mi++) {
#pragma unroll
    for (int r = 0; r < 4; r++) {
      int row = m0 + wm + mi * 16 + quad * 4 + r;
      if (row >= n_e) continue;
      if (MODE == 0) {
        size_t base = (size_t)(h_off[e] + row) * N;
#pragma unroll
        for (int ni = 0; ni < 4; ni++) {
          int col = n0 + wn + ni * 16 + lm;
          float v = acc[mi][ni][r] + bias[e * N + col];
          v = fmaxf(v, 0.f);
          h_out[base + col] = f2bf(v);
        }
      } else {
        int tok = tok_list[e * T_TOK + row];
        float wgt = wgt_list[e * T_TOK + row];
        size_t base = (size_t)tok * N;
#pragma unroll
        for (int ni = 0; ni < 4; ni++) {
          int col = n0 + wn + ni * 16 + lm;
          float v = wgt * (acc[mi][ni][r] + bias[e * N + col]);
          atomicAdd(&out[base + col], v);
        }
      }
    }
  }
}

extern "C" void kernel_launch(void* const* d_in, const int* in_sizes, int n_in,
                              void* d_out, int out_size, void* d_ws, size_t ws_size,
                              hipStream_t stream) {
  const float* x  = (const float*)d_in[0];
  const float* wg = (const float*)d_in[1];
  const float* w1 = (const float*)d_in[2];
  const float* b1 = (const float*)d_in[3];
  const float* w2 = (const float*)d_in[4];
  const float* b2 = (const float*)d_in[5];
  float* out = (float*)d_out;

  char* ws = (char*)d_ws;
  // ws layout (bytes), all 256-aligned; total ~151.5 MB
  int*            counts   = (int*)(ws + 0);
  int*            top1cnt  = (int*)(ws + 32);
  float*          ssum     = (float*)(ws + 64);
  int*            h_off    = (int*)(ws + 96);
  int*            tok_list = (int*)(ws + 256);
  float*          wgt_list = (float*)(ws + 262400);
  unsigned short* x_bf     = (unsigned short*)(ws + 524544);
  unsigned short* w1t      = (unsigned short*)(ws + 17301760);
  unsigned short* w2t      = (unsigned short*)(ws + 50856192);
  unsigned short* h_buf    = (unsigned short*)(ws + 84410624);

  hipMemsetAsync(ws, 0, 256, stream);
  hipMemsetAsync(d_out, 0, (size_t)out_size * sizeof(float), stream);

  dim3 tb(32, 8);
  transpose_cast_kernel<<<dim3(HID / 32, DIM / 32, NE), tb, 0, stream>>>(w1, w1t, DIM, HID);
  transpose_cast_kernel<<<dim3(DIM / 32, HID / 32, NE), tb, 0, stream>>>(w2, w2t, HID, DIM);

  gate_kernel<<<T_TOK / GB_TOK, 256, 0, stream>>>(x, wg, x_bf, counts, top1cnt, ssum,
                                                  tok_list, wgt_list);
  scan_kernel<<<1, 64, 0, stream>>>(counts, top1cnt, ssum, h_off, out + (size_t)T_TOK * DIM);

  // GEMM1: M=n_e, N=HID, K=DIM
  moe_gemm_kernel<0><<<dim3(HID / BN, T_TOK / BM, NE), 512, 0, stream>>>(
      x_bf, w1t, b1, counts, h_off, tok_list, wgt_list, h_buf, nullptr, HID, DIM);
  // GEMM2: M=n_e, N=DIM, K=HID
  moe_gemm_kernel<1><<<dim3(DIM / BN, T_TOK / BM, NE), 512, 0, stream>>>(
      h_buf, w2t, b2, counts, h_off, tok_list, wgt_list, nullptr, out, DIM, HID);
}

// Round 2
// 538.165 us; speedup vs baseline: 1.0666x; 1.0666x over previous
//
#include <hip/hip_runtime.h>
#include <stdint.h>

#define T_TOK 8192
#define DIM   1024
#define HID   2048
#define NE    8

#define BM 256
#define BN 256
#define BK 64

#define GB_TOK 32  // tokens per gate block

typedef float floatx4 __attribute__((ext_vector_type(4)));
typedef short shortx8 __attribute__((ext_vector_type(8)));

typedef __attribute__((address_space(3))) void       lds_void;
typedef const __attribute__((address_space(1))) void gbl_void;

__device__ __forceinline__ unsigned short f2bf(float f) {
  unsigned int u = __float_as_uint(f);
  unsigned int r = 0x7fffu + ((u >> 16) & 1u);
  return (unsigned short)((u + r) >> 16);
}

// ------------- transpose+cast: in [R][C] f32 -> out [C][R] bf16, blockIdx.z = expert -------------
__global__ __launch_bounds__(256) void transpose_cast_kernel(const float* __restrict__ in,
                                                             unsigned short* __restrict__ out,
                                                             int R, int C) {
  __shared__ float tile[32][33];
  const size_t eoff = (size_t)blockIdx.z * R * C;
  const float* ip = in + eoff;
  unsigned short* op = out + eoff;
  int c0 = blockIdx.x * 32, r0 = blockIdx.y * 32;
  int tx = threadIdx.x, ty = threadIdx.y;
#pragma unroll
  for (int i = 0; i < 4; i++)
    tile[ty + i * 8][tx] = ip[(size_t)(r0 + ty + i * 8) * C + (c0 + tx)];
  __syncthreads();
#pragma unroll
  for (int i = 0; i < 4; i++)
    op[(size_t)(c0 + ty + i * 8) * R + (r0 + tx)] = f2bf(tile[tx][ty + i * 8]);
}

// ---------------- gating: 32 tokens/block; also casts x -> bf16 ----------------
__global__ __launch_bounds__(256) void gate_kernel(const float* __restrict__ x,
                                                   const float* __restrict__ wg,
                                                   unsigned short* __restrict__ xb,
                                                   int* counts, int* top1cnt, float* ssum,
                                                   int* tok_list, float* wgt_list) {
  __shared__ int   lds_cnt[8];
  __shared__ int   lds_top1[8];
  __shared__ float lds_ssum[4][8];
  __shared__ int   tk_e[GB_TOK][2];
  __shared__ int   tk_r[GB_TOK][2];
  __shared__ float tk_w[GB_TOK][2];
  __shared__ int   base[8];

  const int tid = threadIdx.x;
  const int wave = tid >> 6;
  const int lane = tid & 63;

  if (tid < 8) { lds_cnt[tid] = 0; lds_top1[tid] = 0; }
  if (tid < 32) lds_ssum[tid >> 3][tid & 7] = 0.f;
  __syncthreads();

  float ssum_local[8];
#pragma unroll
  for (int e = 0; e < 8; e++) ssum_local[e] = 0.f;

  for (int it = 0; it < GB_TOK / 4; it++) {
    const int lt = it * 4 + wave;
    const int t = blockIdx.x * GB_TOK + lt;

    float acc[8];
#pragma unroll
    for (int e = 0; e < 8; e++) acc[e] = 0.f;
    const float* xr = x + (size_t)t * DIM;
    unsigned short* xw = xb + (size_t)t * DIM;
#pragma unroll
    for (int i = 0; i < 16; i++) {
      int d = i * 64 + lane;
      float xv = xr[d];
      xw[d] = f2bf(xv);  // fused f32->bf16 cast
      const float4* wr = reinterpret_cast<const float4*>(wg + d * 8);
      float4 w0 = wr[0], w1 = wr[1];
      acc[0] += xv * w0.x; acc[1] += xv * w0.y; acc[2] += xv * w0.z; acc[3] += xv * w0.w;
      acc[4] += xv * w1.x; acc[5] += xv * w1.y; acc[6] += xv * w1.z; acc[7] += xv * w1.w;
    }
#pragma unroll
    for (int e = 0; e < 8; e++) {
#pragma unroll
      for (int off = 32; off > 0; off >>= 1) acc[e] += __shfl_xor(acc[e], off, 64);
    }
    if (lane == 0) {
      float mx = acc[0];
#pragma unroll
      for (int e = 1; e < 8; e++) mx = fmaxf(mx, acc[e]);
      float s[8], sum = 0.f;
#pragma unroll
      for (int e = 0; e < 8; e++) { s[e] = expf(acc[e] - mx); sum += s[e]; }
      float inv = 1.f / sum;
#pragma unroll
      for (int e = 0; e < 8; e++) { s[e] *= inv; ssum_local[e] += s[e]; }
      // top-2 (strict > : ties -> lower index, matches lax.top_k)
      int i1 = 0;
#pragma unroll
      for (int e = 1; e < 8; e++) if (s[e] > s[i1]) i1 = e;
      int i2 = (i1 == 0) ? 1 : 0;
#pragma unroll
      for (int e = 0; e < 8; e++) if (e != i1 && s[e] > s[i2]) i2 = e;
      atomicAdd(&lds_top1[i1], 1);
      int r1 = atomicAdd(&lds_cnt[i1], 1);
      int r2 = atomicAdd(&lds_cnt[i2], 1);
      tk_e[lt][0] = i1; tk_r[lt][0] = r1; tk_w[lt][0] = s[i1];
      tk_e[lt][1] = i2; tk_r[lt][1] = r2; tk_w[lt][1] = s[i2];
    }
  }
  if (lane == 0) {
#pragma unroll
    for (int e = 0; e < 8; e++) lds_ssum[wave][e] = ssum_local[e];
  }
  __syncthreads();
  if (tid < 8) {
    base[tid] = atomicAdd(&counts[tid], lds_cnt[tid]);
    atomicAdd(&top1cnt[tid], lds_top1[tid]);
    atomicAdd(&ssum[tid],
              lds_ssum[0][tid] + lds_ssum[1][tid] + lds_ssum[2][tid] + lds_ssum[3][tid]);
  }
  __syncthreads();
  if (tid < GB_TOK * 2) {
    int lt = tid >> 1, k = tid & 1;
    int e = tk_e[lt][k];
    int pos = base[e] + tk_r[lt][k];
    tok_list[e * T_TOK + pos] = blockIdx.x * GB_TOK + lt;
    wgt_list[e * T_TOK + pos] = tk_w[lt][k];
  }
}

// ---------------- scan + l_aux + flat tile map ----------------
__global__ void scan_kernel(const int* counts, const int* top1cnt, const float* ssum,
                            int* h_off, int* tile_off, float* laux_out) {
  if (threadIdx.x == 0 && blockIdx.x == 0) {
    int off = 0, toff = 0;
    float l = 0.f;
    for (int e = 0; e < 8; e++) {
      h_off[e] = off;
      tile_off[e] = toff;
      off += counts[e];
      toff += (counts[e] + BM - 1) / BM;
      l += (ssum[e] / (float)T_TOK) * ((float)top1cnt[e] / (float)T_TOK);
    }
    tile_off[8] = toff;
    *laux_out = l * (float)NE;
  }
}

// ---------------- grouped GEMM, 8-phase counted-vmcnt schedule ----------------
// 256x256 tile, BK=64, 8 waves (2M x 4N), LDS [2 buf][2 kk-half][128 lines][128B].
// Each 128B line holds a row-PAIR (32 cols per row per kk-half); 16B slot s of line L
// holds global subchunk s^(L&7)  (swizzle on pre-swizzled global source, linear DMA dest,
// compensated on ds_read -> 8 consecutive lanes hit 8 distinct slots, conflict-free).
// Iteration computes 2 K-tiles (a=2i in buf0, b=2i+1 in buf1), 4 phases each.
// Staging map (each STAGE = one half-tile = 2 global_load_lds/thread), by phase:
//   P1: A.k1(b)->buf1   P2: B.k1(b)->buf1    [buf1.k1 freed at prev P8]
//   P3: A.k0(a+2)->buf0 P4: B.k0(a+2)->buf0  [buf0.k0 freed at P2]   + vmcnt(4)
//   P5: A.k1(a+2)->buf0 P6: B.k1(a+2)->buf0  [buf0.k1 freed at P4]
//   P7: A.k0(b+2)->buf1 P8: B.k0(b+2)->buf1  [buf1.k0 freed at P6]   + vmcnt(4)
// vmcnt(4) at P4/P8 leaves exactly the 2 newest half-tiles in flight; everything a later
// phase reads was confirmed complete >=1 vmcnt earlier (ledger verified incl. prologue).
// MODE 0: A = x_bf gathered via tok_list; epilogue relu(acc+b1) -> h_buf bf16
// MODE 1: A = h_buf rows;                 epilogue atomicAdd(out[tok], w*(acc+b2))

#define LDA4(buf, kk, mh)                                                        \
  do {                                                                           \
    const char* ha_ = (const char*)&s_a[buf][kk][0][0];                          \
    _Pragma("unroll") for (int j_ = 0; j_ < 4; j_++)                             \
        af[j_] = *reinterpret_cast<const shortx8*>(ha_ + aoff + ((mh)*4 + j_) * 1024); \
  } while (0)

#define LDB4(buf, kk)                                                            \
  do {                                                                           \
    const char* hb_ = (const char*)&s_b[buf][kk][0][0];                          \
    _Pragma("unroll") for (int j_ = 0; j_ < 4; j_++)                             \
        bfr[j_] = *reinterpret_cast<const shortx8*>(hb_ + boff + j_ * 1024);     \
  } while (0)

#define MFMA16(mh)                                                               \
  do {                                                                           \
    __builtin_amdgcn_s_setprio(1);                                               \
    _Pragma("unroll") for (int j_ = 0; j_ < 4; j_++)                             \
        _Pragma("unroll") for (int n_ = 0; n_ < 4; n_++)                         \
            acc[(mh)*4 + j_][n_] = __builtin_amdgcn_mfma_f32_16x16x32_bf16(      \
                af[j_], bfr[n_], acc[(mh)*4 + j_][n_], 0, 0, 0);                 \
    __builtin_amdgcn_s_setprio(0);                                               \
  } while (0)

#define STAGE_A(buf, kk, tile)                                                   \
  do {                                                                           \
    __builtin_amdgcn_global_load_lds((gbl_void*)(a_p0 + (size_t)(tile)*64 + (kk)*32), \
                                     (lds_void*)&s_a[buf][kk][wv * 8][0], 16, 0, 0);  \
    __builtin_amdgcn_global_load_lds((gbl_void*)(a_p1 + (size_t)(tile)*64 + (kk)*32), \
                                     (lds_void*)&s_a[buf][kk][64 + wv * 8][0], 16, 0, 0); \
  } while (0)

#define STAGE_B(buf, kk, tile)                                                   \
  do {                                                                           \
    __builtin_amdgcn_global_load_lds((gbl_void*)(b_p0 + (size_t)(tile)*64 + (kk)*32), \
                                     (lds_void*)&s_b[buf][kk][wv * 8][0], 16, 0, 0);  \
    __builtin_amdgcn_global_load_lds((gbl_void*)(b_p1 + (size_t)(tile)*64 + (kk)*32), \
                                     (lds_void*)&s_b[buf][kk][64 + wv * 8][0], 16, 0, 0); \
  } while (0)

#define BAR()                                                                    \
  do { __builtin_amdgcn_s_barrier(); asm volatile("" ::: "memory"); } while (0)
#define BARW()                                                                   \
  do {                                                                           \
    __builtin_amdgcn_s_barrier();                                                \
    asm volatile("s_waitcnt lgkmcnt(0)" ::: "memory");                           \
  } while (0)
#define VM4() asm volatile("s_waitcnt vmcnt(4)" ::: "memory")

template <int MODE>
__global__ __launch_bounds__(512, 2) void moe_gemm_kernel(
    const unsigned short* __restrict__ A_src, const unsigned short* __restrict__ B_src,
    const float* __restrict__ bias, const int* __restrict__ counts,
    const int* __restrict__ h_off, const int* __restrict__ tile_off,
    const int* __restrict__ tok_list, const float* __restrict__ wgt_list,
    unsigned short* __restrict__ h_out, float* __restrict__ out, int N, int K) {
  __shared__ unsigned short s_a[2][2][128][64];  // 64 KB  (buf, kk-half, line, 128B)
  __shared__ unsigned short s_b[2][2][128][64];  // 64 KB

  const int bt = blockIdx.y;
  if (bt >= tile_off[8]) return;
  int e = 7;
#pragma unroll
  for (int q = 6; q >= 0; q--)
    if (bt < tile_off[q + 1]) e = q;
  const int n_e = counts[e];
  const int m0 = (bt - tile_off[e]) * BM;
  const int n0 = blockIdx.x * BN;
  const int tid = threadIdx.x;

  const int lane = tid & 63;
  const int wv = tid >> 6;  // 0..7

  // ---- staging geometry: thread -> (line, slot) -> swizzled global (row, chunk) ----
  const int slot = tid & 7;
  const int Lr = tid >> 3;            // line within round, 0..63
  const int g = slot ^ (Lr & 7);      // global subchunk held at this LDS slot
  const int rbase = 2 * Lr + (g >> 2);  // tile row within round's 128 rows
  const int cc8 = (g & 3) * 8;          // element offset of 16B chunk within 32-col half

  const unsigned short *a_p0, *a_p1, *b_p0, *b_p1;
  {
    int gr0 = m0 + rbase, gr1 = m0 + 128 + rbase;
    int s0 = (gr0 < n_e) ? gr0 : (n_e - 1);  // clamp: garbage only feeds discarded C rows
    int s1 = (gr1 < n_e) ? gr1 : (n_e - 1);
    if (MODE == 0) {
      a_p0 = A_src + (size_t)tok_list[e * T_TOK + s0] * K + cc8;
      a_p1 = A_src + (size_t)tok_list[e * T_TOK + s1] * K + cc8;
    } else {
      a_p0 = A_src + (size_t)(h_off[e] + s0) * K + cc8;
      a_p1 = A_src + (size_t)(h_off[e] + s1) * K + cc8;
    }
    b_p0 = B_src + ((size_t)e * N + n0 + rbase) * K + cc8;
    b_p1 = B_src + ((size_t)e * N + n0 + 128 + rbase) * K + cc8;
  }

  // ---- read geometry ----
  const int lm = lane & 15;
  const int quad = lane >> 4;
  const int wm = (wv >> 2) * 128;  // wave M-offset (2 waves in M)
  const int wn = (wv & 3) * 64;    // wave N-offset (4 waves in N)
  const int phys = (((lm & 1) << 2) | quad) ^ (lm >> 1);
  const int aoff = (((wm >> 1) + (lm >> 1)) << 7) + (phys << 4);  // bytes in kk-half
  const int boff = (((wn >> 1) + (lm >> 1)) << 7) + (phys << 4);

  floatx4 acc[8][4];
#pragma unroll
  for (int mi = 0; mi < 8; mi++)
#pragma unroll
    for (int ni = 0; ni < 4; ni++) acc[mi][ni] = (floatx4){0.f, 0.f, 0.f, 0.f};

  const int NT = K / BK;  // 16 or 32 (even)
  const int NI = NT / 2;

  // ---- prologue: tile0 (all), tile1.k0 ; vmcnt(4) -> tile0 complete ----
  STAGE_A(0, 0, 0); STAGE_B(0, 0, 0);
  STAGE_A(0, 1, 0); STAGE_B(0, 1, 0);
  STAGE_A(1, 0, 1); STAGE_B(1, 0, 1);
  asm volatile("s_waitcnt vmcnt(4)" ::: "memory");
  BAR();

  for (int i = 0; i < NI; ++i) {
    const int tb = 2 * i + 1;
    const int a2 = (2 * i + 2 < NT) ? (2 * i + 2) : (NT - 1);  // clamped: dummy but in-bounds
    const int b2 = (2 * i + 3 < NT) ? (2 * i + 3) : (NT - 1);
    shortx8 af[4], bfr[4];
    // ---- K-tile a = 2i (buf 0) ----
    LDA4(0, 0, 0); LDB4(0, 0); STAGE_A(1, 1, tb);        BARW(); MFMA16(0); BAR();  // P1
    LDA4(0, 0, 1);             STAGE_B(1, 1, tb);        BARW(); MFMA16(1); BAR();  // P2
    LDA4(0, 1, 0); LDB4(0, 1); STAGE_A(0, 0, a2);        BARW(); MFMA16(0); BAR();  // P3
    LDA4(0, 1, 1);             STAGE_B(0, 0, a2); VM4(); BARW(); MFMA16(1); BAR();  // P4
    // ---- K-tile b = 2i+1 (buf 1) ----
    LDA4(1, 0, 0); LDB4(1, 0); STAGE_A(0, 1, a2);        BARW(); MFMA16(0); BAR();  // P5
    LDA4(1, 0, 1);             STAGE_B(0, 1, a2);        BARW(); MFMA16(1); BAR();  // P6
    LDA4(1, 1, 0); LDB4(1, 1); STAGE_A(1, 0, b2);        BARW(); MFMA16(0); BAR();  // P7
    LDA4(1, 1, 1);             STAGE_B(1, 0, b2); VM4(); BARW(); MFMA16(1); BAR();  // P8
  }

  // drain DMA before end-of-block (protect next workgroup's LDS on this CU)
  asm volatile("s_waitcnt vmcnt(0)" ::: "memory");

  // epilogue: D row = quad*4 + r, col = lm (verified C/D layout)
#pragma unroll
  for (int mi = 0; mi < 8; mi++) {
#pragma unroll
    for (int r = 0; r < 4; r++) {
      int row = m0 + wm + mi * 16 + quad * 4 + r;
      if (row >= n_e) continue;
      if (MODE == 0) {
        size_t base = (size_t)(h_off[e] + row) * N;
#pragma unroll
        for (int ni = 0; ni < 4; ni++) {
          int col = n0 + wn + ni * 16 + lm;
          float v = acc[mi][ni][r] + bias[e * N + col];
          v = fmaxf(v, 0.f);
          h_out[base + col] = f2bf(v);
        }
      } else {
        int tok = tok_list[e * T_TOK + row];
        float wgt = wgt_list[e * T_TOK + row];
        size_t base = (size_t)tok * N;
#pragma unroll
        for (int ni = 0; ni < 4; ni++) {
          int col = n0 + wn + ni * 16 + lm;
          float v = wgt * (acc[mi][ni][r] + bias[e * N + col]);
          atomicAdd(&out[base + col], v);
        }
      }
    }
  }
}

extern "C" void kernel_launch(void* const* d_in, const int* in_sizes, int n_in,
                              void* d_out, int out_size, void* d_ws, size_t ws_size,
                              hipStream_t stream) {
  const float* x  = (const float*)d_in[0];
  const float* wg = (const float*)d_in[1];
  const float* w1 = (const float*)d_in[2];
  const float* b1 = (const float*)d_in[3];
  const float* w2 = (const float*)d_in[4];
  const float* b2 = (const float*)d_in[5];
  float* out = (float*)d_out;

  char* ws = (char*)d_ws;
  // ws layout (bytes), all 256-aligned; total ~151.5 MB
  int*            counts   = (int*)(ws + 0);
  int*            top1cnt  = (int*)(ws + 32);
  float*          ssum     = (float*)(ws + 64);
  int*            h_off    = (int*)(ws + 96);
  int*            tile_off = (int*)(ws + 128);   // 9 ints
  int*            tok_list = (int*)(ws + 256);
  float*          wgt_list = (float*)(ws + 262400);
  unsigned short* x_bf     = (unsigned short*)(ws + 524544);
  unsigned short* w1t      = (unsigned short*)(ws + 17301760);
  unsigned short* w2t      = (unsigned short*)(ws + 50856192);
  unsigned short* h_buf    = (unsigned short*)(ws + 84410624);

  hipMemsetAsync(ws, 0, 256, stream);
  hipMemsetAsync(d_out, 0, (size_t)out_size * sizeof(float), stream);

  dim3 tb(32, 8);
  transpose_cast_kernel<<<dim3(HID / 32, DIM / 32, NE), tb, 0, stream>>>(w1, w1t, DIM, HID);
  transpose_cast_kernel<<<dim3(DIM / 32, HID / 32, NE), tb, 0, stream>>>(w2, w2t, HID, DIM);

  gate_kernel<<<T_TOK / GB_TOK, 256, 0, stream>>>(x, wg, x_bf, counts, top1cnt, ssum,
                                                  tok_list, wgt_list);
  scan_kernel<<<1, 64, 0, stream>>>(counts, top1cnt, ssum, h_off, tile_off,
                                    out + (size_t)T_TOK * DIM);

  // max flat tiles = sum_e ceil(n_e/256) <= 16384/256 + 8 = 72
  // GEMM1: M=n_e, N=HID, K=DIM
  moe_gemm_kernel<0><<<dim3(HID / BN, 72, 1), 512, 0, stream>>>(
      x_bf, w1t, b1, counts, h_off, tile_off, tok_list, wgt_list, h_buf, nullptr, HID, DIM);
  // GEMM2: M=n_e, N=DIM, K=HID
  moe_gemm_kernel<1><<<dim3(DIM / BN, 72, 1), 512, 0, stream>>>(
      h_buf, w2t, b2, counts, h_off, tile_off, tok_list, wgt_list, nullptr, out, DIM, HID);
}